// Round 1
// 356.908 us; speedup vs baseline: 1.0005x; 1.0005x over previous
//
#include <hip/hip_runtime.h>

#define N_NODES 50000
#define N_EDGES 1600000
#define F_IN 8
#define HID 1000
#define R_OUT 100

#define BSHIFT 6               // bucket = dst >> 6
#define NPB 64                 // nodes per bucket
#define NB 782                 // ceil(50000/64)
#define CAP_B 2432             // per-bucket capacity; mean 2048, +8.5 sigma
#define CHUNK 4096             // edges per bin block
#define NBIN_BLOCKS ((N_EDGES + CHUNK - 1) / CHUNK)   // 391
#define NCHUNK0 25             // gemv0 split-K chunks (50000/25=2000, /4 ok)

// ======================= helpers =======================

__device__ __forceinline__ unsigned fkey(float f) {
    unsigned b = __float_as_uint(f);
    return (b & 0x80000000u) ? ~b : (b | 0x80000000u);
}
__device__ __forceinline__ float funkey(unsigned k) {
    unsigned b = (k & 0x80000000u) ? (k & 0x7fffffffu) : ~k;
    return __uint_as_float(b);
}

// zero the cursor/ovf region and seed h0 with b0 (gemv0 accumulates into it)
__global__ void init_kernel(unsigned* __restrict__ p, int nzero,
                            const float* __restrict__ b0, float* __restrict__ h0) {
    int i = blockIdx.x * blockDim.x + threadIdx.x;
    if (i < nzero) p[i] = 0u;
    if (i < HID) h0[i] = b0[i];
}

// ======================= pass 1: LDS-staged binning =======================
// Phase A reads ei once (int4-vectorized), staging packed entries + bucket ids
// in LDS while building the per-bucket histogram. Phase B reserves global
// ranges (1 atomic per nonzero (block,bucket)). Phase C scatters from LDS.
__global__ void bin_kernel(const int* __restrict__ ei,
                           const float* __restrict__ X,
                           const float* __restrict__ wl,
                           int* __restrict__ cursor,        // [NB]
                           unsigned* __restrict__ binned,   // [NB*CAP_B]
                           int* __restrict__ ovf_cnt,
                           float* __restrict__ ovf_sum,
                           unsigned* __restrict__ ovf_max) {
    __shared__ unsigned sEntry[CHUNK];        // 16 KB
    __shared__ unsigned short sBucket[CHUNK]; // 8 KB
    __shared__ int hist[NB];                  // 3.1 KB
    __shared__ int pos[NB];
    __shared__ int base[NB];
    int tid = threadIdx.x;
    int e0 = blockIdx.x * CHUNK;
    int e1 = e0 + CHUNK;
    if (e1 > N_EDGES) e1 = N_EDGES;
    int ne = e1 - e0;              // always a multiple of 4 (last block: 2560)

    for (int i = tid; i < NB; i += 256) { hist[i] = 0; pos[i] = 0; }
    __syncthreads();

    // phase A: single vectorized read of ei; stage + histogram
    const int4* s4 = (const int4*)(ei + e0);
    const int4* d4 = (const int4*)(ei + N_EDGES + e0);
    int n4 = ne >> 2;
    for (int j4 = tid; j4 < n4; j4 += 256) {
        int4 s = s4[j4];
        int4 d = d4[j4];
        int jj = j4 << 2;
        int sv[4] = {s.x, s.y, s.z, s.w};
        int dv[4] = {d.x, d.y, d.z, d.w};
#pragma unroll
        for (int m = 0; m < 4; ++m) {
            int b = dv[m] >> BSHIFT;
            sEntry[jj + m] = (unsigned)sv[m] | ((unsigned)(dv[m] & (NPB - 1)) << 16);
            sBucket[jj + m] = (unsigned short)b;
            atomicAdd(&hist[b], 1);
        }
    }
    __syncthreads();

    // phase B: reserve contiguous ranges in global bucket lists
    for (int b = tid; b < NB; b += 256) {
        int h = hist[b];
        base[b] = (h > 0) ? atomicAdd(&cursor[b], h) : 0;
    }
    __syncthreads();

    // phase C: ranked scatter from LDS
    for (int j = tid; j < ne; j += 256) {
        unsigned entry = sEntry[j];
        int b = sBucket[j];
        int p = atomicAdd(&pos[b], 1);
        int gp = base[b] + p;
        if (gp < CAP_B) {
            binned[(size_t)b * CAP_B + gp] = entry;
        } else {
            // exact overflow path (statistically never taken)
            int src = entry & 0xFFFF;
            int dst = b * NPB + (int)(entry >> 16);
            const float4* X4 = (const float4*)(X + src * F_IN);
            float4 a = X4[0], bb = X4[1];
            float f[8] = {a.x, a.y, a.z, a.w, bb.x, bb.y, bb.z, bb.w};
            float dacc = 0.f;
#pragma unroll
            for (int k = 0; k < 8; ++k) dacc += f[k] * wl[k];
            atomicAdd(&ovf_cnt[dst], 1);
            atomicAdd(&ovf_sum[dst], dacc);
            unsigned* mb = ovf_max + (size_t)dst * 8;
#pragma unroll
            for (int k = 0; k < 8; ++k) atomicMax(&mb[k], fkey(f[k]));
        }
    }
}

// ======================= pass 2: sort-free LDS-atomic aggregation =======================
// One 256-thread block per bucket (64 nodes). Each edge directly accumulates
// into per-node LDS partials (f32 add + u32 max); no staging, no counting
// sort, no serial prefix. sMax is feature-major so lanes hit bank d%32.
__global__ void agg_kernel(const int* __restrict__ cursor,
                           const unsigned* __restrict__ binned,
                           const int* __restrict__ ovf_cnt,
                           const float* __restrict__ ovf_sum,
                           const unsigned* __restrict__ ovf_max,
                           const float* __restrict__ X,
                           const float* __restrict__ lin_l_w,
                           const float* __restrict__ lin_l_b,
                           const float* __restrict__ lin_r_w,
                           const float* __restrict__ lin_l1_w,
                           const float* __restrict__ lin_l1_b,
                           const float* __restrict__ lin_r1_w,
                           float* __restrict__ xemb) {
    __shared__ float sSum[NPB];          // 256 B
    __shared__ int   sCnt[NPB];          // 256 B
    __shared__ unsigned sMax[8][NPB];    // 2 KB, feature-major

    int b = blockIdx.x;
    int tid = threadIdx.x;
    int n = cursor[b];
    if (n > CAP_B) n = CAP_B;

    if (tid < NPB) { sSum[tid] = 0.f; sCnt[tid] = 0; }
    for (int i = tid; i < 8 * NPB; i += 256) ((unsigned*)sMax)[i] = 0u;  // 0 < fkey(any finite)
    __syncthreads();

    float wl[8];
#pragma unroll
    for (int k = 0; k < 8; ++k) wl[k] = lin_l_w[k];

    const unsigned* blist = binned + (size_t)b * CAP_B;
    for (int j = tid; j < n; j += 256) {
        unsigned e = blist[j];
        int src = e & 0xFFFF;
        int d = e >> 16;
        const float4* X4 = (const float4*)(X + src * F_IN);
        float4 a = X4[0], c = X4[1];
        float f[8] = {a.x, a.y, a.z, a.w, c.x, c.y, c.z, c.w};
        float dot = 0.f;
#pragma unroll
        for (int k = 0; k < 8; ++k) dot += f[k] * wl[k];
        atomicAdd(&sSum[d], dot);
        atomicAdd(&sCnt[d], 1);
#pragma unroll
        for (int k = 0; k < 8; ++k) atomicMax(&sMax[k][d], fkey(f[k]));
    }
    __syncthreads();

    // epilogue: one thread per node, coalesced write
    if (tid < NPB) {
        int node = b * NPB + tid;
        if (node < N_NODES) {
            int oc = ovf_cnt[node];
            int total = sCnt[tid] + oc;
            float sd = sSum[tid] + ovf_sum[node];
            unsigned km[8];
#pragma unroll
            for (int k = 0; k < 8; ++k) km[k] = sMax[k][tid];
            if (oc > 0) {
                const unsigned* mb = ovf_max + (size_t)node * 8;
#pragma unroll
                for (int k = 0; k < 8; ++k) km[k] = (km[k] > mb[k]) ? km[k] : mb[k];
            }
            float c = (float)total;
            float mean_dot = sd / fmaxf(c, 1.0f);
            const float4* X4 = (const float4*)(X + node * F_IN);
            float4 a = X4[0], bb = X4[1];
            float f[8] = {a.x, a.y, a.z, a.w, bb.x, bb.y, bb.z, bb.w};
            float dr = 0.f, dr1 = 0.f, dmax = 0.f;
            bool nonempty = (total > 0);
#pragma unroll
            for (int k = 0; k < 8; ++k) {
                float m = nonempty ? funkey(km[k]) : 0.0f;
                dmax += m * lin_l1_w[k];
                dr   += f[k] * lin_r_w[k];
                dr1  += f[k] * lin_r1_w[k];
            }
            float hm = fmaxf(mean_dot + lin_l_b[0] + dr, 0.f);
            float hx = fmaxf(dmax + lin_l1_b[0] + dr1, 0.f);
            xemb[node] = hm + hx;
        }
    }
}

// ======================= GEMV =======================

// split-K gemv accumulating atomically into y (pre-seeded with bias).
// grid: (NCHUNK, rows) -> consecutive blocks read consecutive chunks (sequential HBM).
template <int BLOCK, int NCHUNK>
__global__ void gemv_accum(const float* __restrict__ W,
                           const float* __restrict__ x,
                           float* __restrict__ y, int cols) {
    int c = blockIdx.x;
    int row = blockIdx.y;
    int chunk = cols / NCHUNK;
    const float4* W4 = (const float4*)(W + (size_t)row * cols + (size_t)c * chunk);
    const float4* x4 = (const float4*)(x + c * chunk);
    int n4 = chunk >> 2;
    float s = 0.f;
    for (int j = threadIdx.x; j < n4; j += BLOCK) {
        float4 w = W4[j], xx = x4[j];
        s += w.x * xx.x + w.y * xx.y + w.z * xx.z + w.w * xx.w;
    }
#pragma unroll
    for (int off = 32; off > 0; off >>= 1) s += __shfl_down(s, off, 64);
    __shared__ float red[BLOCK / 64];
    int t = threadIdx.x;
    if ((t & 63) == 0) red[t >> 6] = s;
    __syncthreads();
    if (t == 0) {
        float tot = 0.f;
#pragma unroll
        for (int w = 0; w < BLOCK / 64; ++w) tot += red[w];
        atomicAdd(&y[row], tot);
    }
}

// block-per-row GEMV; optionally applies ReLU to x elements on load.
template <int BLOCK, bool RELUX>
__global__ void gemv_relu(const float* __restrict__ W,
                          const float* __restrict__ x,
                          const float* __restrict__ bias,
                          float* __restrict__ y, int cols) {
    int row = blockIdx.x;
    const float4* W4 = (const float4*)(W + (size_t)row * cols);
    const float4* x4 = (const float4*)x;
    int n4 = cols >> 2;
    float s = 0.f;
    for (int j = threadIdx.x; j < n4; j += BLOCK) {
        float4 w = W4[j], xx = x4[j];
        if (RELUX) {
            xx.x = fmaxf(xx.x, 0.f); xx.y = fmaxf(xx.y, 0.f);
            xx.z = fmaxf(xx.z, 0.f); xx.w = fmaxf(xx.w, 0.f);
        }
        s += w.x * xx.x + w.y * xx.y + w.z * xx.z + w.w * xx.w;
    }
#pragma unroll
    for (int off = 32; off > 0; off >>= 1) s += __shfl_down(s, off, 64);
    __shared__ float red[BLOCK / 64];
    int t = threadIdx.x;
    if ((t & 63) == 0) red[t >> 6] = s;
    __syncthreads();
    if (t == 0) {
        float tot = 0.f;
#pragma unroll
        for (int w = 0; w < BLOCK / 64; ++w) tot += red[w];
        y[row] = fmaxf(tot + bias[row], 0.f);
    }
}

// ======================= fallback (round-1 atomic path) =======================

__global__ void init_ws_fb(unsigned* __restrict__ p, int n) {
    int i = blockIdx.x * blockDim.x + threadIdx.x;
    if (i < n) p[i] = 0u;
}

__global__ void edge_kernel_fb(const int* __restrict__ ei,
                               const float* __restrict__ X,
                               const float* __restrict__ wl,
                               float* __restrict__ sumw,
                               float* __restrict__ cnt,
                               unsigned* __restrict__ maxb) {
    int e = blockIdx.x * blockDim.x + threadIdx.x;
    if (e >= N_EDGES) return;
    int src = ei[e];
    int dst = ei[N_EDGES + e];
    const float4* X4 = (const float4*)(X + src * F_IN);
    float4 a = X4[0], b = X4[1];
    float f[8] = {a.x, a.y, a.z, a.w, b.x, b.y, b.z, b.w};
    float d = 0.f;
#pragma unroll
    for (int k = 0; k < 8; ++k) d += f[k] * wl[k];
    atomicAdd(&sumw[dst], d);
    atomicAdd(&cnt[dst], 1.0f);
    unsigned* mb = maxb + (size_t)dst * 8;
#pragma unroll
    for (int k = 0; k < 8; ++k) atomicMax(&mb[k], fkey(f[k]));
}

__global__ void node_kernel_fb(const float* __restrict__ X,
                               const float* __restrict__ sumw,
                               const float* __restrict__ cnt,
                               const unsigned* __restrict__ maxb,
                               const float* __restrict__ lin_l_b,
                               const float* __restrict__ lin_r_w,
                               const float* __restrict__ lin_l1_w,
                               const float* __restrict__ lin_l1_b,
                               const float* __restrict__ lin_r1_w,
                               float* __restrict__ xout) {
    int i = blockIdx.x * blockDim.x + threadIdx.x;
    if (i >= N_NODES) return;
    float c = cnt[i];
    float mean_dot = sumw[i] / fmaxf(c, 1.0f);
    const float4* X4 = (const float4*)(X + i * F_IN);
    float4 a = X4[0], b = X4[1];
    float f[8] = {a.x, a.y, a.z, a.w, b.x, b.y, b.z, b.w};
    const uint4* M4 = (const uint4*)(maxb + (size_t)i * 8);
    uint4 m0 = M4[0], m1 = M4[1];
    unsigned mk[8] = {m0.x, m0.y, m0.z, m0.w, m1.x, m1.y, m1.z, m1.w};
    float dr = 0.f, dr1 = 0.f, dmax = 0.f;
    bool nonempty = (c > 0.f);
#pragma unroll
    for (int k = 0; k < 8; ++k) {
        float mxv = nonempty ? funkey(mk[k]) : 0.0f;
        dmax += mxv * lin_l1_w[k];
        dr   += f[k] * lin_r_w[k];
        dr1  += f[k] * lin_r1_w[k];
    }
    float hm = fmaxf(mean_dot + lin_l_b[0] + dr, 0.f);
    float hx = fmaxf(dmax + lin_l1_b[0] + dr1, 0.f);
    xout[i] = hm + hx;
}

// ======================= launch =======================

extern "C" void kernel_launch(void* const* d_in, const int* in_sizes, int n_in,
                              void* d_out, int out_size, void* d_ws, size_t ws_size,
                              hipStream_t stream) {
    const float* X        = (const float*)d_in[0];
    const int*   ei       = (const int*)d_in[1];
    const float* lin_l_w  = (const float*)d_in[2];
    const float* lin_l_b  = (const float*)d_in[3];
    const float* lin_r_w  = (const float*)d_in[4];
    const float* lin_l1_w = (const float*)d_in[5];
    const float* lin_l1_b = (const float*)d_in[6];
    const float* lin_r1_w = (const float*)d_in[7];
    const float* W0       = (const float*)d_in[8];
    const float* b0       = (const float*)d_in[9];
    const float* W1       = (const float*)d_in[10];
    const float* b1       = (const float*)d_in[11];
    const float* W2       = (const float*)d_in[12];
    const float* b2       = (const float*)d_in[13];

    float* xemb = (float*)d_out;
    float* out2 = xemb + N_NODES;

    // ws layout (words): zeroed first: [cursor NB][ovf_cnt N][ovf_sum N][ovf_max N*8]
    // then: [binned NB*CAP_B][h0 HID][h1 HID]
    const size_t zero_words = (size_t)NB + (size_t)N_NODES * 10;
    const size_t need_words = zero_words + (size_t)NB * CAP_B + 2 * HID;
    if (ws_size >= need_words * 4) {
        int*      cursor  = (int*)d_ws;                            // [NB]
        int*      ovf_cnt = cursor + NB;                           // [N]
        float*    ovf_sum = (float*)(ovf_cnt + N_NODES);           // [N]
        unsigned* ovf_max = (unsigned*)(ovf_sum + N_NODES);        // [N*8]
        unsigned* binned  = ovf_max + (size_t)N_NODES * 8;         // [NB*CAP_B]
        float*    h0      = (float*)(binned + (size_t)NB * CAP_B); // [HID]
        float*    h1      = h0 + HID;                              // [HID]

        hipLaunchKernelGGL(init_kernel, dim3(((int)zero_words + 255) / 256), dim3(256), 0, stream,
                           (unsigned*)d_ws, (int)zero_words, b0, h0);
        hipLaunchKernelGGL(bin_kernel, dim3(NBIN_BLOCKS), dim3(256), 0, stream,
                           ei, X, lin_l_w, cursor, binned, ovf_cnt, ovf_sum, ovf_max);
        hipLaunchKernelGGL(agg_kernel, dim3(NB), dim3(256), 0, stream,
                           cursor, binned, ovf_cnt, ovf_sum, ovf_max, X,
                           lin_l_w, lin_l_b, lin_r_w, lin_l1_w, lin_l1_b, lin_r1_w, xemb);

        hipLaunchKernelGGL((gemv_accum<256, NCHUNK0>), dim3(NCHUNK0, HID), dim3(256), 0, stream,
                           W0, xemb, h0, N_NODES);
        hipLaunchKernelGGL((gemv_relu<256, true>), dim3(HID), dim3(256), 0, stream,
                           W1, h0, b1, h1, HID);
        hipLaunchKernelGGL((gemv_relu<256, false>), dim3(R_OUT), dim3(256), 0, stream,
                           W2, h1, b2, out2, HID);
    } else {
        float*    sumw = (float*)d_ws;
        float*    cntf = sumw + N_NODES;
        unsigned* maxb = (unsigned*)(cntf + N_NODES);
        float*    h0   = (float*)(maxb + (size_t)N_NODES * 8);
        float*    h1   = h0 + HID;

        int zw = N_NODES * 10;
        hipLaunchKernelGGL(init_ws_fb, dim3((zw + 255) / 256), dim3(256), 0, stream,
                           (unsigned*)d_ws, zw);
        hipLaunchKernelGGL(edge_kernel_fb, dim3((N_EDGES + 255) / 256), dim3(256), 0, stream,
                           ei, X, lin_l_w, sumw, cntf, maxb);
        hipLaunchKernelGGL(node_kernel_fb, dim3((N_NODES + 255) / 256), dim3(256), 0, stream,
                           X, sumw, cntf, maxb, lin_l_b, lin_r_w, lin_l1_w, lin_l1_b,
                           lin_r1_w, xemb);
        hipLaunchKernelGGL((gemv_relu<256, false>), dim3(HID), dim3(256), 0, stream,
                           W0, xemb, b0, h0, N_NODES);
        hipLaunchKernelGGL((gemv_relu<256, false>), dim3(HID), dim3(256), 0, stream,
                           W1, h0, b1, h1, HID);
        hipLaunchKernelGGL((gemv_relu<256, false>), dim3(R_OUT), dim3(256), 0, stream,
                           W2, h1, b2, out2, HID);
    }
}